// Round 3
// baseline (658.901 us; speedup 1.0000x reference)
//
#include <hip/hip_runtime.h>

#define N_ITEMS   100000
#define N_BASKETS 50000
#define NNZ       1000000
#define D         128
#define NUM_LAYER 3

#define SCAN_BLOCKS 256
#define SCAN_TPB    256

#define NPART      8      // destination partitions == XCDs
#define PART_GRID  2048   // 256 blocks per partition group

// ---------------- destination-partitioned histogram ----------------
// group g = blockIdx & 7 only counts rows in partition g -> count lines owned by
// one XCD L2. Input stream is non-temporal so count lines stay resident.
__global__ void k_hist2(const int* __restrict__ b_rows, const int* __restrict__ i_rows,
                        int* __restrict__ b_count, int* __restrict__ i_count) {
    int part = blockIdx.x & (NPART - 1);
    int blk  = blockIdx.x >> 3;
    int tid  = blk * blockDim.x + threadIdx.x;
    int stride = (PART_GRID / NPART) * blockDim.x;
    const int PB = (N_BASKETS + NPART - 1) / NPART;   // 6250
    const int PI = (N_ITEMS + NPART - 1) / NPART;     // 12500
    int blo = part * PB, bhi = blo + PB;
    for (int i = tid; i < NNZ; i += stride) {
        int r = __builtin_nontemporal_load(b_rows + i);
        if (r >= blo && r < bhi) atomicAdd(&b_count[r], 1);
    }
    int ilo = part * PI, ihi = ilo + PI;
    for (int i = tid; i < NNZ; i += stride) {
        int r = __builtin_nontemporal_load(i_rows + i);
        if (r >= ilo && r < ihi) atomicAdd(&i_count[r], 1);
    }
}

// ---------------- hierarchical exclusive scan, both arrays in one pass ----------------
__global__ void k_chunk_sums2(const int* __restrict__ b_in, const int* __restrict__ i_in,
                              int* __restrict__ bsums) {
    __shared__ int lds[SCAN_TPB];
    int blk = blockIdx.x;
    const int* in; int n; int b;
    if (blk < SCAN_BLOCKS) { in = b_in; n = N_BASKETS + 1; b = blk; }
    else                   { in = i_in; n = N_ITEMS + 1;   b = blk - SCAN_BLOCKS; }
    int chunk = (n + SCAN_BLOCKS - 1) / SCAN_BLOCKS;
    int s = b * chunk;
    int e = min(s + chunk, n);
    int acc = 0;
    for (int i = s + (int)threadIdx.x; i < e; i += SCAN_TPB) acc += in[i];
    lds[threadIdx.x] = acc;
    __syncthreads();
    for (int o = SCAN_TPB / 2; o > 0; o >>= 1) {
        if ((int)threadIdx.x < o) lds[threadIdx.x] += lds[threadIdx.x + o];
        __syncthreads();
    }
    if (threadIdx.x == 0) bsums[blk] = lds[0];
}

__global__ void k_exscan2(int* __restrict__ bsums) {
    __shared__ int lds[SCAN_TPB];
    int* p = bsums + blockIdx.x * SCAN_BLOCKS;
    int v = p[threadIdx.x];
    lds[threadIdx.x] = v;
    __syncthreads();
    for (int o = 1; o < SCAN_TPB; o <<= 1) {
        int t = ((int)threadIdx.x >= o) ? lds[threadIdx.x - o] : 0;
        __syncthreads();
        lds[threadIdx.x] += t;
        __syncthreads();
    }
    p[threadIdx.x] = lds[threadIdx.x] - v; // exclusive
}

// also seeds fill[] = row_ptr[] so the scatter needs only one atomicAdd
__global__ void k_scan_write2(const int* __restrict__ b_in, const int* __restrict__ i_in,
                              const int* __restrict__ bsums,
                              int* __restrict__ b_out, int* __restrict__ i_out,
                              int* __restrict__ b_fill, int* __restrict__ i_fill) {
    __shared__ int lds[SCAN_TPB];
    int blk = blockIdx.x;
    const int* in; int* out; int* fill; int n; int b;
    if (blk < SCAN_BLOCKS) { in = b_in; out = b_out; fill = b_fill; n = N_BASKETS + 1; b = blk; }
    else                   { in = i_in; out = i_out; fill = i_fill; n = N_ITEMS + 1;   b = blk - SCAN_BLOCKS; }
    int chunk = (n + SCAN_BLOCKS - 1) / SCAN_BLOCKS;
    int s = b * chunk;
    int e = min(s + chunk, n);
    int carry = bsums[blk];
    for (int base = s; base < e; base += SCAN_TPB) {
        int i = base + (int)threadIdx.x;
        int v = (i < e) ? in[i] : 0;
        lds[threadIdx.x] = v;
        __syncthreads();
        for (int o = 1; o < SCAN_TPB; o <<= 1) {
            int t = ((int)threadIdx.x >= o) ? lds[threadIdx.x - o] : 0;
            __syncthreads();
            lds[threadIdx.x] += t;
            __syncthreads();
        }
        if (i < e) {
            int val = carry + lds[threadIdx.x] - v;
            out[i] = val;
            if (i < n - 1) fill[i] = val;   // seed fill cursor
        }
        int tot = lds[SCAN_TPB - 1];
        __syncthreads();
        carry += tot;
    }
}

// ---------------- destination-partitioned scatter into packed (col,val) CSR --------
// All input streams non-temporal: per-XCD L2 holds only its 2MB ev partition +
// fill cursors, so each ev line collects all its entries before one writeback.
__global__ void k_scatter2(const int* __restrict__ b_rows, const int* __restrict__ b_cols,
                           const float* __restrict__ b_vals,
                           const int* __restrict__ i_rows, const int* __restrict__ i_cols,
                           const float* __restrict__ i_vals,
                           int* __restrict__ b_fill, int* __restrict__ i_fill,
                           int2* __restrict__ b_ev, int2* __restrict__ i_ev) {
    int part = blockIdx.x & (NPART - 1);
    int blk  = blockIdx.x >> 3;
    int tid  = blk * blockDim.x + threadIdx.x;
    int stride = (PART_GRID / NPART) * blockDim.x;
    const int PB = (N_BASKETS + NPART - 1) / NPART;
    const int PI = (N_ITEMS + NPART - 1) / NPART;
    int blo = part * PB, bhi = blo + PB;
    for (int i = tid; i < NNZ; i += stride) {
        int r = __builtin_nontemporal_load(b_rows + i);
        if (r >= blo && r < bhi) {
            int c = __builtin_nontemporal_load(b_cols + i);
            int v = __builtin_nontemporal_load((const int*)b_vals + i);
            int pos = atomicAdd(&b_fill[r], 1);
            b_ev[pos] = make_int2(c, v);
        }
    }
    int ilo = part * PI, ihi = ilo + PI;
    for (int i = tid; i < NNZ; i += stride) {
        int r = __builtin_nontemporal_load(i_rows + i);
        if (r >= ilo && r < ihi) {
            int c = __builtin_nontemporal_load(i_cols + i);
            int v = __builtin_nontemporal_load((const int*)i_vals + i);
            int pos = atomicAdd(&i_fill[r], 1);
            i_ev[pos] = make_int2(c, v);
        }
    }
}

// ---------------- CSR SpMM: one 64-lane wave per row, 8-deep pipelined gather ------
// ev stream loaded non-temporal (sequential, no reuse) so gather-source lines
// keep L2 residency. MODE semantics unchanged.
template<int MODE>
__global__ __launch_bounds__(256) void k_spmm(const int* __restrict__ row_ptr,
                                              const int2* __restrict__ ev,
                                              const float* __restrict__ dense,
                                              float* out, float* sum,
                                              const float* a0, const float* a1,
                                              const float* a2,
                                              int n_rows) {
    int wv   = threadIdx.x >> 6;
    int lane = threadIdx.x & 63;
    int row  = blockIdx.x * 4 + wv;
    if (row >= n_rows) return;
    int beg = row_ptr[row];
    int end = row_ptr[row + 1];
    beg = __builtin_amdgcn_readfirstlane(beg);
    end = __builtin_amdgcn_readfirstlane(end);

    const char* dbase = reinterpret_cast<const char*>(dense) + (size_t)lane * 8;
    const long long* evq = reinterpret_cast<const long long*>(ev);
    float ax = 0.f, ay = 0.f;
    int e = beg;
    // 8 outstanding 512B gathers per wave
    for (; e + 8 <= end; e += 8) {
        long long q0 = __builtin_nontemporal_load(evq + e + 0);
        long long q1 = __builtin_nontemporal_load(evq + e + 1);
        long long q2 = __builtin_nontemporal_load(evq + e + 2);
        long long q3 = __builtin_nontemporal_load(evq + e + 3);
        long long q4 = __builtin_nontemporal_load(evq + e + 4);
        long long q5 = __builtin_nontemporal_load(evq + e + 5);
        long long q6 = __builtin_nontemporal_load(evq + e + 6);
        long long q7 = __builtin_nontemporal_load(evq + e + 7);
        float2 d0 = *reinterpret_cast<const float2*>(dbase + ((size_t)(int)q0 << 9));
        float2 d1 = *reinterpret_cast<const float2*>(dbase + ((size_t)(int)q1 << 9));
        float2 d2 = *reinterpret_cast<const float2*>(dbase + ((size_t)(int)q2 << 9));
        float2 d3 = *reinterpret_cast<const float2*>(dbase + ((size_t)(int)q3 << 9));
        float2 d4 = *reinterpret_cast<const float2*>(dbase + ((size_t)(int)q4 << 9));
        float2 d5 = *reinterpret_cast<const float2*>(dbase + ((size_t)(int)q5 << 9));
        float2 d6 = *reinterpret_cast<const float2*>(dbase + ((size_t)(int)q6 << 9));
        float2 d7 = *reinterpret_cast<const float2*>(dbase + ((size_t)(int)q7 << 9));
        float v0 = __int_as_float((int)(q0 >> 32)), v1 = __int_as_float((int)(q1 >> 32));
        float v2 = __int_as_float((int)(q2 >> 32)), v3 = __int_as_float((int)(q3 >> 32));
        float v4 = __int_as_float((int)(q4 >> 32)), v5 = __int_as_float((int)(q5 >> 32));
        float v6 = __int_as_float((int)(q6 >> 32)), v7 = __int_as_float((int)(q7 >> 32));
        ax = fmaf(v0, d0.x, ax); ay = fmaf(v0, d0.y, ay);
        ax = fmaf(v1, d1.x, ax); ay = fmaf(v1, d1.y, ay);
        ax = fmaf(v2, d2.x, ax); ay = fmaf(v2, d2.y, ay);
        ax = fmaf(v3, d3.x, ax); ay = fmaf(v3, d3.y, ay);
        ax = fmaf(v4, d4.x, ax); ay = fmaf(v4, d4.y, ay);
        ax = fmaf(v5, d5.x, ax); ay = fmaf(v5, d5.y, ay);
        ax = fmaf(v6, d6.x, ax); ay = fmaf(v6, d6.y, ay);
        ax = fmaf(v7, d7.x, ax); ay = fmaf(v7, d7.y, ay);
    }
    for (; e + 4 <= end; e += 4) {
        long long q0 = __builtin_nontemporal_load(evq + e + 0);
        long long q1 = __builtin_nontemporal_load(evq + e + 1);
        long long q2 = __builtin_nontemporal_load(evq + e + 2);
        long long q3 = __builtin_nontemporal_load(evq + e + 3);
        float2 d0 = *reinterpret_cast<const float2*>(dbase + ((size_t)(int)q0 << 9));
        float2 d1 = *reinterpret_cast<const float2*>(dbase + ((size_t)(int)q1 << 9));
        float2 d2 = *reinterpret_cast<const float2*>(dbase + ((size_t)(int)q2 << 9));
        float2 d3 = *reinterpret_cast<const float2*>(dbase + ((size_t)(int)q3 << 9));
        float v0 = __int_as_float((int)(q0 >> 32)), v1 = __int_as_float((int)(q1 >> 32));
        float v2 = __int_as_float((int)(q2 >> 32)), v3 = __int_as_float((int)(q3 >> 32));
        ax = fmaf(v0, d0.x, ax); ay = fmaf(v0, d0.y, ay);
        ax = fmaf(v1, d1.x, ax); ay = fmaf(v1, d1.y, ay);
        ax = fmaf(v2, d2.x, ax); ay = fmaf(v2, d2.y, ay);
        ax = fmaf(v3, d3.x, ax); ay = fmaf(v3, d3.y, ay);
    }
    if (e + 2 <= end) {
        long long q0 = __builtin_nontemporal_load(evq + e + 0);
        long long q1 = __builtin_nontemporal_load(evq + e + 1);
        float2 d0 = *reinterpret_cast<const float2*>(dbase + ((size_t)(int)q0 << 9));
        float2 d1 = *reinterpret_cast<const float2*>(dbase + ((size_t)(int)q1 << 9));
        float v0 = __int_as_float((int)(q0 >> 32)), v1 = __int_as_float((int)(q1 >> 32));
        ax = fmaf(v0, d0.x, ax); ay = fmaf(v0, d0.y, ay);
        ax = fmaf(v1, d1.x, ax); ay = fmaf(v1, d1.y, ay);
        e += 2;
    }
    if (e < end) {
        long long q0 = __builtin_nontemporal_load(evq + e);
        float2 d0 = *reinterpret_cast<const float2*>(dbase + ((size_t)(int)q0 << 9));
        float v0 = __int_as_float((int)(q0 >> 32));
        ax = fmaf(v0, d0.x, ax); ay = fmaf(v0, d0.y, ay);
    }

    size_t o = (size_t)row * D + (size_t)lane * 2;
    float2 r = make_float2(ax, ay);
    if (MODE == 0) {
        *reinterpret_cast<float2*>(out + o) = r;
    } else if (MODE == 1) {
        *reinterpret_cast<float2*>(out + o) = r;
        *reinterpret_cast<float2*>(sum + o) = r;
    } else if (MODE == 2) {
        *reinterpret_cast<float2*>(out + o) = r;
        float2 s = *reinterpret_cast<const float2*>(sum + o);
        s.x += r.x; s.y += r.y;
        *reinterpret_cast<float2*>(sum + o) = s;
    } else if (MODE == 3) {
        *reinterpret_cast<float2*>(out + o) = r;
        float2 s = *reinterpret_cast<const float2*>(sum + o);
        s.x = (s.x + r.x) * (1.0f / 3.0f);
        s.y = (s.y + r.y) * (1.0f / 3.0f);
        *reinterpret_cast<float2*>(sum + o) = s;
    } else { // MODE 4
        float2 s0 = *reinterpret_cast<const float2*>(a0 + o);
        float2 s1 = *reinterpret_cast<const float2*>(a1 + o);
        float2 s2 = *reinterpret_cast<const float2*>(a2 + o);
        r.x = (s0.x + s1.x + s2.x + r.x) * 0.25f;
        r.y = (s0.y + s1.y + s2.y + r.y) * 0.25f;
        *reinterpret_cast<float2*>(out + o) = r;
    }
}

extern "C" void kernel_launch(void* const* d_in, const int* in_sizes, int n_in,
                              void* d_out, int out_size, void* d_ws, size_t ws_size,
                              hipStream_t stream) {
    const float* x      = (const float*)d_in[0];
    const int*   b_rows = (const int*)  d_in[1];
    const int*   b_cols = (const int*)  d_in[2];
    const float* b_vals = (const float*)d_in[3];
    const int*   i_rows = (const int*)  d_in[4];
    const int*   i_cols = (const int*)  d_in[5];
    const float* i_vals = (const float*)d_in[6];

    float* out        = (float*)d_out;
    float* out_item   = out;                              // [N_ITEMS * D]; doubles as cur1 storage
    float* out_basket = out + (size_t)N_ITEMS * D;        // [N_BASKETS * D]

    char* ws = (char*)d_ws;
    size_t off = 0;
    auto alloc = [&](size_t bytes) -> char* {
        char* p = ws + off;
        off = (off + bytes + 255) & ~(size_t)255;
        return p;
    };
    int*   cnt       = (int*)  alloc((size_t)(N_BASKETS + N_ITEMS + 2) * sizeof(int));
    int*   b_count   = cnt;
    int*   i_count   = cnt + (N_BASKETS + 1);
    int*   b_row_ptr = (int*)  alloc((N_BASKETS + 1) * sizeof(int));
    int*   i_row_ptr = (int*)  alloc((N_ITEMS + 1) * sizeof(int));
    int*   fills     = (int*)  alloc((size_t)(N_BASKETS + N_ITEMS) * sizeof(int));
    int*   b_fill    = fills;
    int*   i_fill    = fills + N_BASKETS;
    int*   bsums     = (int*)  alloc(2 * SCAN_BLOCKS * sizeof(int));
    int2*  b_ev      = (int2*) alloc((size_t)NNZ * sizeof(int2));
    int2*  i_ev      = (int2*) alloc((size_t)NNZ * sizeof(int2));
    float* basket_buf= (float*)alloc((size_t)N_BASKETS * D * sizeof(float));
    float* cur2      = (float*)alloc((size_t)N_ITEMS * D * sizeof(float));
    (void)ws_size; (void)in_sizes; (void)n_in; (void)out_size;

    // -------- build both CSRs (destination-partitioned, XCD-pinned, nt streams) ----
    hipMemsetAsync(cnt, 0, (size_t)(N_BASKETS + N_ITEMS + 2) * sizeof(int), stream);
    k_hist2<<<PART_GRID, 256, 0, stream>>>(b_rows, i_rows, b_count, i_count);
    k_chunk_sums2<<<2 * SCAN_BLOCKS, SCAN_TPB, 0, stream>>>(b_count, i_count, bsums);
    k_exscan2<<<2, SCAN_TPB, 0, stream>>>(bsums);
    k_scan_write2<<<2 * SCAN_BLOCKS, SCAN_TPB, 0, stream>>>(b_count, i_count, bsums,
                                                            b_row_ptr, i_row_ptr,
                                                            b_fill, i_fill);
    k_scatter2<<<PART_GRID, 256, 0, stream>>>(b_rows, b_cols, b_vals,
                                              i_rows, i_cols, i_vals,
                                              b_fill, i_fill, b_ev, i_ev);

    const int GB = (N_BASKETS + 3) / 4;
    const int GI = (N_ITEMS + 3) / 4;

    // -------- layer 1 --------
    k_spmm<1><<<GB, 256, 0, stream>>>(b_row_ptr, b_ev, x, basket_buf, out_basket,
                                      nullptr, nullptr, nullptr, N_BASKETS);
    k_spmm<0><<<GI, 256, 0, stream>>>(i_row_ptr, i_ev, basket_buf, out_item, nullptr,
                                      nullptr, nullptr, nullptr, N_ITEMS);
    // -------- layer 2 --------
    k_spmm<2><<<GB, 256, 0, stream>>>(b_row_ptr, b_ev, out_item, basket_buf, out_basket,
                                      nullptr, nullptr, nullptr, N_BASKETS);
    k_spmm<0><<<GI, 256, 0, stream>>>(i_row_ptr, i_ev, basket_buf, cur2, nullptr,
                                      nullptr, nullptr, nullptr, N_ITEMS);
    // -------- layer 3 --------
    k_spmm<3><<<GB, 256, 0, stream>>>(b_row_ptr, b_ev, cur2, basket_buf, out_basket,
                                      nullptr, nullptr, nullptr, N_BASKETS);
    k_spmm<4><<<GI, 256, 0, stream>>>(i_row_ptr, i_ev, basket_buf, out_item, nullptr,
                                      x, out_item, cur2, N_ITEMS);
}

// Round 4
// 539.073 us; speedup vs baseline: 1.2223x; 1.2223x over previous
//
#include <hip/hip_runtime.h>

#define N_ITEMS   100000
#define N_BASKETS 50000
#define NNZ       1000000
#define D         128

// ---------------- atomic-free CSR build: two-level counting sort ----------------
#define NBLK   256                         // chunks == blocks in hist/route
#define TPB    256
#define CH     ((NNZ + NBLK - 1) / NBLK)   // 3907 elements per chunk
#define NBUK   391                         // buckets per matrix
#define SHIFT_B 7                          // 128 basket rows per bucket (391*128 >= 50000)
#define SHIFT_I 8                          // 256 item rows per bucket   (391*256 >= 100000)

// chunk id swizzle: chunks 0..31 -> XCD0 blocks, 32..63 -> XCD1, ... so that
// adjacent staging slices (consecutive chunk ids within a bucket) are written by
// blocks on the same XCD -> no cross-XCD false sharing on slice-boundary lines.
__device__ __forceinline__ int chunk_of_block() {
    return ((blockIdx.x & 7) << 5) | (blockIdx.x >> 3);
}

// pass 1a: per-(chunk,bucket) counts. LDS atomics only.
__global__ __launch_bounds__(256) void k_bucket_hist(
        const int* __restrict__ b_rows, const int* __restrict__ i_rows,
        int* __restrict__ tableB, int* __restrict__ tableI) {
    __shared__ int cnt[NBUK];
    int chunk = chunk_of_block();
    int s = chunk * CH, e = min(s + CH, NNZ);
    for (int j = threadIdx.x; j < NBUK; j += TPB) cnt[j] = 0;
    __syncthreads();
    for (int i = s + (int)threadIdx.x; i < e; i += TPB)
        atomicAdd(&cnt[b_rows[i] >> SHIFT_B], 1);
    __syncthreads();
    for (int j = threadIdx.x; j < NBUK; j += TPB) tableB[chunk * NBUK + j] = cnt[j];
    __syncthreads();
    for (int j = threadIdx.x; j < NBUK; j += TPB) cnt[j] = 0;
    __syncthreads();
    for (int i = s + (int)threadIdx.x; i < e; i += TPB)
        atomicAdd(&cnt[i_rows[i] >> SHIFT_I], 1);
    __syncthreads();
    for (int j = threadIdx.x; j < NBUK; j += TPB) tableI[chunk * NBUK + j] = cnt[j];
}

// pass 2a: per-bucket exclusive scan over the 256 chunk counts (in place),
// bucket total out. blockIdx encodes (matrix, bucket).
__global__ __launch_bounds__(256) void k_col_scan(int* __restrict__ tableB,
                                                  int* __restrict__ tableI,
                                                  int* __restrict__ tot) {
    __shared__ int lds[NBLK];
    int id = blockIdx.x;               // 0..2*NBUK-1
    int m = id / NBUK, b = id % NBUK;
    int* tbl = m ? tableI : tableB;
    int t = threadIdx.x;               // == chunk id
    int v = tbl[t * NBUK + b];
    lds[t] = v;
    __syncthreads();
    for (int o = 1; o < NBLK; o <<= 1) {
        int tv = (t >= o) ? lds[t - o] : 0;
        __syncthreads();
        lds[t] += tv;
        __syncthreads();
    }
    tbl[t * NBUK + b] = lds[t] - v;    // exclusive offset of chunk t within bucket b
    if (t == NBLK - 1) tot[m * NBUK + b] = lds[t];
}

// pass 2b: exclusive scan of bucket totals -> bucket element bases.
__global__ __launch_bounds__(512) void k_base_scan(const int* __restrict__ tot,
                                                   int* __restrict__ base) {
    __shared__ int lds[512];
    int m = blockIdx.x;
    int t = threadIdx.x;
    int v = (t < NBUK) ? tot[m * NBUK + t] : 0;
    lds[t] = v;
    __syncthreads();
    for (int o = 1; o < 512; o <<= 1) {
        int tv = (t >= o) ? lds[t - o] : 0;
        __syncthreads();
        lds[t] += tv;
        __syncthreads();
    }
    if (t < NBUK) base[m * NBUK + t] = lds[t] - v;
}

// pass 1b: route COO into bucket-grouped staging. LDS cursors (base+chunkoff)
// give each element a unique slot; zero global atomics.
__global__ __launch_bounds__(256) void k_route(
        const int* __restrict__ b_rows, const int* __restrict__ b_cols,
        const float* __restrict__ b_vals,
        const int* __restrict__ i_rows, const int* __restrict__ i_cols,
        const float* __restrict__ i_vals,
        const int* __restrict__ tableB, const int* __restrict__ tableI,
        const int* __restrict__ base,
        int* __restrict__ stg_rowB, int2* __restrict__ stg_cvB,
        int* __restrict__ stg_rowI, int2* __restrict__ stg_cvI) {
    __shared__ int cur[NBUK];
    int chunk = chunk_of_block();
    int s = chunk * CH, e = min(s + CH, NNZ);
    for (int j = threadIdx.x; j < NBUK; j += TPB)
        cur[j] = base[j] + tableB[chunk * NBUK + j];
    __syncthreads();
    for (int i = s + (int)threadIdx.x; i < e; i += TPB) {
        int r = b_rows[i];
        int c = b_cols[i];
        float v = b_vals[i];
        int p = atomicAdd(&cur[r >> SHIFT_B], 1);   // LDS atomic
        stg_rowB[p] = r;
        stg_cvB[p] = make_int2(c, __float_as_int(v));
    }
    __syncthreads();
    for (int j = threadIdx.x; j < NBUK; j += TPB)
        cur[j] = base[NBUK + j] + tableI[chunk * NBUK + j];
    __syncthreads();
    for (int i = s + (int)threadIdx.x; i < e; i += TPB) {
        int r = i_rows[i];
        int c = i_cols[i];
        float v = i_vals[i];
        int p = atomicAdd(&cur[r >> SHIFT_I], 1);   // LDS atomic
        stg_rowI[p] = r;
        stg_cvI[p] = make_int2(c, __float_as_int(v));
    }
}

// pass 3: per-bucket counting sort -> final CSR ev + row_ptr. One block per bucket.
__global__ __launch_bounds__(256) void k_bucket_sort(
        const int* __restrict__ stg_rowB, const int2* __restrict__ stg_cvB,
        const int* __restrict__ stg_rowI, const int2* __restrict__ stg_cvI,
        const int* __restrict__ base, const int* __restrict__ tot,
        int* __restrict__ b_row_ptr, int* __restrict__ i_row_ptr,
        int2* __restrict__ b_ev, int2* __restrict__ i_ev) {
    __shared__ int hist[256];
    __shared__ int scn[256];
    __shared__ int cursor[256];
    int id = blockIdx.x;
    int m = id / NBUK, b = id % NBUK;
    const int*  srow = m ? stg_rowI : stg_rowB;
    const int2* scv  = m ? stg_cvI  : stg_cvB;
    int2* ev = m ? i_ev : b_ev;
    int*  rp = m ? i_row_ptr : b_row_ptr;
    int shift = m ? SHIFT_I : SHIFT_B;
    int nrows = m ? N_ITEMS : N_BASKETS;
    int rpb   = 1 << shift;
    int rowbase = b << shift;
    int seg = base[m * NBUK + b];
    int cnt = tot[m * NBUK + b];
    int t = threadIdx.x;

    hist[t] = 0;
    __syncthreads();
    for (int i = t; i < cnt; i += TPB)
        atomicAdd(&hist[srow[seg + i] - rowbase], 1);
    __syncthreads();
    int v = hist[t];
    scn[t] = v;
    __syncthreads();
    for (int o = 1; o < 256; o <<= 1) {
        int tv = (t >= o) ? scn[t - o] : 0;
        __syncthreads();
        scn[t] += tv;
        __syncthreads();
    }
    int excl = scn[t] - v;
    int nlocal = min(rpb, nrows - rowbase);
    if (t < nlocal) rp[rowbase + t] = seg + excl;
    if (t == 0 && rowbase + nlocal == nrows) rp[nrows] = NNZ;
    cursor[t] = excl;
    __syncthreads();
    for (int i = t; i < cnt; i += TPB) {
        int r = srow[seg + i];
        int p = atomicAdd(&cursor[r - rowbase], 1);   // LDS atomic
        ev[seg + p] = scv[seg + i];
    }
}

// ---------------- CSR SpMM: one 64-lane wave per row, 8-deep pipelined gather ------
// MODE 0: out = acc
// MODE 1: out = acc; sum = acc
// MODE 2: out = acc; sum += acc
// MODE 3: out = acc; sum = (sum + acc)/3
// MODE 4: out = (a0 + a1 + a2 + acc)/4
template<int MODE>
__global__ __launch_bounds__(256) void k_spmm(const int* __restrict__ row_ptr,
                                              const int2* __restrict__ ev,
                                              const float* __restrict__ dense,
                                              float* out, float* sum,
                                              const float* a0, const float* a1,
                                              const float* a2,
                                              int n_rows) {
    int wv   = threadIdx.x >> 6;
    int lane = threadIdx.x & 63;
    int row  = blockIdx.x * 4 + wv;
    if (row >= n_rows) return;
    int beg = row_ptr[row];
    int end = row_ptr[row + 1];
    beg = __builtin_amdgcn_readfirstlane(beg);
    end = __builtin_amdgcn_readfirstlane(end);

    const char* dbase = reinterpret_cast<const char*>(dense) + (size_t)lane * 8;
    float ax = 0.f, ay = 0.f;
    int e = beg;
    for (; e + 8 <= end; e += 8) {
        int2 p0 = ev[e + 0], p1 = ev[e + 1], p2 = ev[e + 2], p3 = ev[e + 3];
        int2 p4 = ev[e + 4], p5 = ev[e + 5], p6 = ev[e + 6], p7 = ev[e + 7];
        float2 d0 = *reinterpret_cast<const float2*>(dbase + ((size_t)p0.x << 9));
        float2 d1 = *reinterpret_cast<const float2*>(dbase + ((size_t)p1.x << 9));
        float2 d2 = *reinterpret_cast<const float2*>(dbase + ((size_t)p2.x << 9));
        float2 d3 = *reinterpret_cast<const float2*>(dbase + ((size_t)p3.x << 9));
        float2 d4 = *reinterpret_cast<const float2*>(dbase + ((size_t)p4.x << 9));
        float2 d5 = *reinterpret_cast<const float2*>(dbase + ((size_t)p5.x << 9));
        float2 d6 = *reinterpret_cast<const float2*>(dbase + ((size_t)p6.x << 9));
        float2 d7 = *reinterpret_cast<const float2*>(dbase + ((size_t)p7.x << 9));
        float v0 = __int_as_float(p0.y), v1 = __int_as_float(p1.y);
        float v2 = __int_as_float(p2.y), v3 = __int_as_float(p3.y);
        float v4 = __int_as_float(p4.y), v5 = __int_as_float(p5.y);
        float v6 = __int_as_float(p6.y), v7 = __int_as_float(p7.y);
        ax = fmaf(v0, d0.x, ax); ay = fmaf(v0, d0.y, ay);
        ax = fmaf(v1, d1.x, ax); ay = fmaf(v1, d1.y, ay);
        ax = fmaf(v2, d2.x, ax); ay = fmaf(v2, d2.y, ay);
        ax = fmaf(v3, d3.x, ax); ay = fmaf(v3, d3.y, ay);
        ax = fmaf(v4, d4.x, ax); ay = fmaf(v4, d4.y, ay);
        ax = fmaf(v5, d5.x, ax); ay = fmaf(v5, d5.y, ay);
        ax = fmaf(v6, d6.x, ax); ay = fmaf(v6, d6.y, ay);
        ax = fmaf(v7, d7.x, ax); ay = fmaf(v7, d7.y, ay);
    }
    for (; e + 4 <= end; e += 4) {
        int2 p0 = ev[e + 0], p1 = ev[e + 1], p2 = ev[e + 2], p3 = ev[e + 3];
        float2 d0 = *reinterpret_cast<const float2*>(dbase + ((size_t)p0.x << 9));
        float2 d1 = *reinterpret_cast<const float2*>(dbase + ((size_t)p1.x << 9));
        float2 d2 = *reinterpret_cast<const float2*>(dbase + ((size_t)p2.x << 9));
        float2 d3 = *reinterpret_cast<const float2*>(dbase + ((size_t)p3.x << 9));
        float v0 = __int_as_float(p0.y), v1 = __int_as_float(p1.y);
        float v2 = __int_as_float(p2.y), v3 = __int_as_float(p3.y);
        ax = fmaf(v0, d0.x, ax); ay = fmaf(v0, d0.y, ay);
        ax = fmaf(v1, d1.x, ax); ay = fmaf(v1, d1.y, ay);
        ax = fmaf(v2, d2.x, ax); ay = fmaf(v2, d2.y, ay);
        ax = fmaf(v3, d3.x, ax); ay = fmaf(v3, d3.y, ay);
    }
    if (e + 2 <= end) {
        int2 p0 = ev[e], p1 = ev[e + 1];
        float2 d0 = *reinterpret_cast<const float2*>(dbase + ((size_t)p0.x << 9));
        float2 d1 = *reinterpret_cast<const float2*>(dbase + ((size_t)p1.x << 9));
        float v0 = __int_as_float(p0.y), v1 = __int_as_float(p1.y);
        ax = fmaf(v0, d0.x, ax); ay = fmaf(v0, d0.y, ay);
        ax = fmaf(v1, d1.x, ax); ay = fmaf(v1, d1.y, ay);
        e += 2;
    }
    if (e < end) {
        int2 p0 = ev[e];
        float2 d0 = *reinterpret_cast<const float2*>(dbase + ((size_t)p0.x << 9));
        float v0 = __int_as_float(p0.y);
        ax = fmaf(v0, d0.x, ax); ay = fmaf(v0, d0.y, ay);
    }

    size_t o = (size_t)row * D + (size_t)lane * 2;
    float2 r = make_float2(ax, ay);
    if (MODE == 0) {
        *reinterpret_cast<float2*>(out + o) = r;
    } else if (MODE == 1) {
        *reinterpret_cast<float2*>(out + o) = r;
        *reinterpret_cast<float2*>(sum + o) = r;
    } else if (MODE == 2) {
        *reinterpret_cast<float2*>(out + o) = r;
        float2 s = *reinterpret_cast<const float2*>(sum + o);
        s.x += r.x; s.y += r.y;
        *reinterpret_cast<float2*>(sum + o) = s;
    } else if (MODE == 3) {
        *reinterpret_cast<float2*>(out + o) = r;
        float2 s = *reinterpret_cast<const float2*>(sum + o);
        s.x = (s.x + r.x) * (1.0f / 3.0f);
        s.y = (s.y + r.y) * (1.0f / 3.0f);
        *reinterpret_cast<float2*>(sum + o) = s;
    } else { // MODE 4
        float2 s0 = *reinterpret_cast<const float2*>(a0 + o);
        float2 s1 = *reinterpret_cast<const float2*>(a1 + o);
        float2 s2 = *reinterpret_cast<const float2*>(a2 + o);
        r.x = (s0.x + s1.x + s2.x + r.x) * 0.25f;
        r.y = (s0.y + s1.y + s2.y + r.y) * 0.25f;
        *reinterpret_cast<float2*>(out + o) = r;
    }
}

extern "C" void kernel_launch(void* const* d_in, const int* in_sizes, int n_in,
                              void* d_out, int out_size, void* d_ws, size_t ws_size,
                              hipStream_t stream) {
    const float* x      = (const float*)d_in[0];
    const int*   b_rows = (const int*)  d_in[1];
    const int*   b_cols = (const int*)  d_in[2];
    const float* b_vals = (const float*)d_in[3];
    const int*   i_rows = (const int*)  d_in[4];
    const int*   i_cols = (const int*)  d_in[5];
    const float* i_vals = (const float*)d_in[6];

    float* out        = (float*)d_out;
    float* out_item   = out;                              // [N_ITEMS * D]; doubles as cur1
    float* out_basket = out + (size_t)N_ITEMS * D;        // [N_BASKETS * D]

    char* ws = (char*)d_ws;
    size_t off = 0;
    auto alloc = [&](size_t bytes) -> char* {
        char* p = ws + off;
        off = (off + bytes + 255) & ~(size_t)255;
        return p;
    };
    int*   tableB    = (int*)  alloc((size_t)NBLK * NBUK * sizeof(int));
    int*   tableI    = (int*)  alloc((size_t)NBLK * NBUK * sizeof(int));
    int*   tot       = (int*)  alloc(2 * NBUK * sizeof(int));
    int*   base      = (int*)  alloc(2 * NBUK * sizeof(int));
    int*   b_row_ptr = (int*)  alloc((N_BASKETS + 1) * sizeof(int));
    int*   i_row_ptr = (int*)  alloc((N_ITEMS + 1) * sizeof(int));
    int2*  b_ev      = (int2*) alloc((size_t)NNZ * sizeof(int2));
    int2*  i_ev      = (int2*) alloc((size_t)NNZ * sizeof(int2));
    float* basket_buf= (float*)alloc((size_t)N_BASKETS * D * sizeof(float));
    float* cur2      = (float*)alloc((size_t)N_ITEMS * D * sizeof(float));
    // staging aliases cur2 (dead by the time cur2 is first written in layer 2)
    char*  stg       = (char*)cur2;
    int*   stg_rowB  = (int*) stg;                                    // 4 MB
    int2*  stg_cvB   = (int2*)(stg + (size_t)NNZ * sizeof(int));      // 8 MB
    int*   stg_rowI  = (int*) (stg + (size_t)NNZ * 12);               // 4 MB
    int2*  stg_cvI   = (int2*)(stg + (size_t)NNZ * 16);               // 8 MB
    (void)ws_size; (void)in_sizes; (void)n_in; (void)out_size;

    // -------- atomic-free CSR build --------
    k_bucket_hist<<<NBLK, TPB, 0, stream>>>(b_rows, i_rows, tableB, tableI);
    k_col_scan<<<2 * NBUK, NBLK, 0, stream>>>(tableB, tableI, tot);
    k_base_scan<<<2, 512, 0, stream>>>(tot, base);
    k_route<<<NBLK, TPB, 0, stream>>>(b_rows, b_cols, b_vals,
                                      i_rows, i_cols, i_vals,
                                      tableB, tableI, base,
                                      stg_rowB, stg_cvB, stg_rowI, stg_cvI);
    k_bucket_sort<<<2 * NBUK, 256, 0, stream>>>(stg_rowB, stg_cvB, stg_rowI, stg_cvI,
                                                base, tot,
                                                b_row_ptr, i_row_ptr, b_ev, i_ev);

    const int GB = (N_BASKETS + 3) / 4;
    const int GI = (N_ITEMS + 3) / 4;

    // -------- layer 1 --------
    k_spmm<1><<<GB, 256, 0, stream>>>(b_row_ptr, b_ev, x, basket_buf, out_basket,
                                      nullptr, nullptr, nullptr, N_BASKETS);
    k_spmm<0><<<GI, 256, 0, stream>>>(i_row_ptr, i_ev, basket_buf, out_item, nullptr,
                                      nullptr, nullptr, nullptr, N_ITEMS);
    // -------- layer 2 --------
    k_spmm<2><<<GB, 256, 0, stream>>>(b_row_ptr, b_ev, out_item, basket_buf, out_basket,
                                      nullptr, nullptr, nullptr, N_BASKETS);
    k_spmm<0><<<GI, 256, 0, stream>>>(i_row_ptr, i_ev, basket_buf, cur2, nullptr,
                                      nullptr, nullptr, nullptr, N_ITEMS);
    // -------- layer 3 --------
    k_spmm<3><<<GB, 256, 0, stream>>>(b_row_ptr, b_ev, cur2, basket_buf, out_basket,
                                      nullptr, nullptr, nullptr, N_BASKETS);
    k_spmm<4><<<GI, 256, 0, stream>>>(i_row_ptr, i_ev, basket_buf, out_item, nullptr,
                                      x, out_item, cur2, N_ITEMS);
}

// Round 5
// 352.766 us; speedup vs baseline: 1.8678x; 1.5281x over previous
//
#include <hip/hip_runtime.h>
#include <hip/hip_fp16.h>

#define N_ITEMS   100000
#define N_BASKETS 50000
#define NNZ       1000000
#define D         128

// ---------------- atomic-free CSR build: two-level counting sort ----------------
#define NBLK   256                         // chunks == blocks in hist/route
#define TPB    256
#define CH     ((NNZ + NBLK - 1) / NBLK)   // 3907 elements per chunk
#define NBUK   391                         // buckets per matrix
#define SHIFT_B 7                          // 128 basket rows per bucket
#define SHIFT_I 8                          // 256 item rows per bucket

__device__ __forceinline__ int chunk_of_block() {
    return ((blockIdx.x & 7) << 5) | (blockIdx.x >> 3);
}

// pass 1a: per-(chunk,bucket) counts. LDS atomics only.
__global__ __launch_bounds__(256) void k_bucket_hist(
        const int* __restrict__ b_rows, const int* __restrict__ i_rows,
        int* __restrict__ tableB, int* __restrict__ tableI) {
    __shared__ int cnt[NBUK];
    int chunk = chunk_of_block();
    int s = chunk * CH, e = min(s + CH, NNZ);
    for (int j = threadIdx.x; j < NBUK; j += TPB) cnt[j] = 0;
    __syncthreads();
    for (int i = s + (int)threadIdx.x; i < e; i += TPB)
        atomicAdd(&cnt[b_rows[i] >> SHIFT_B], 1);
    __syncthreads();
    for (int j = threadIdx.x; j < NBUK; j += TPB) tableB[chunk * NBUK + j] = cnt[j];
    __syncthreads();
    for (int j = threadIdx.x; j < NBUK; j += TPB) cnt[j] = 0;
    __syncthreads();
    for (int i = s + (int)threadIdx.x; i < e; i += TPB)
        atomicAdd(&cnt[i_rows[i] >> SHIFT_I], 1);
    __syncthreads();
    for (int j = threadIdx.x; j < NBUK; j += TPB) tableI[chunk * NBUK + j] = cnt[j];
}

// pass 2a: per-bucket exclusive scan over chunk counts (in place), bucket total out.
__global__ __launch_bounds__(256) void k_col_scan(int* __restrict__ tableB,
                                                  int* __restrict__ tableI,
                                                  int* __restrict__ tot) {
    __shared__ int lds[NBLK];
    int id = blockIdx.x;
    int m = id / NBUK, b = id % NBUK;
    int* tbl = m ? tableI : tableB;
    int t = threadIdx.x;
    int v = tbl[t * NBUK + b];
    lds[t] = v;
    __syncthreads();
    for (int o = 1; o < NBLK; o <<= 1) {
        int tv = (t >= o) ? lds[t - o] : 0;
        __syncthreads();
        lds[t] += tv;
        __syncthreads();
    }
    tbl[t * NBUK + b] = lds[t] - v;
    if (t == NBLK - 1) tot[m * NBUK + b] = lds[t];
}

// pass 2b: exclusive scan of bucket totals -> bucket element bases.
__global__ __launch_bounds__(512) void k_base_scan(const int* __restrict__ tot,
                                                   int* __restrict__ base) {
    __shared__ int lds[512];
    int m = blockIdx.x;
    int t = threadIdx.x;
    int v = (t < NBUK) ? tot[m * NBUK + t] : 0;
    lds[t] = v;
    __syncthreads();
    for (int o = 1; o < 512; o <<= 1) {
        int tv = (t >= o) ? lds[t - o] : 0;
        __syncthreads();
        lds[t] += tv;
        __syncthreads();
    }
    if (t < NBUK) base[m * NBUK + t] = lds[t] - v;
}

// pass 1b: route COO into bucket-grouped staging. LDS cursors; zero global atomics.
__global__ __launch_bounds__(256) void k_route(
        const int* __restrict__ b_rows, const int* __restrict__ b_cols,
        const float* __restrict__ b_vals,
        const int* __restrict__ i_rows, const int* __restrict__ i_cols,
        const float* __restrict__ i_vals,
        const int* __restrict__ tableB, const int* __restrict__ tableI,
        const int* __restrict__ base,
        int* __restrict__ stg_rowB, int2* __restrict__ stg_cvB,
        int* __restrict__ stg_rowI, int2* __restrict__ stg_cvI) {
    __shared__ int cur[NBUK];
    int chunk = chunk_of_block();
    int s = chunk * CH, e = min(s + CH, NNZ);
    for (int j = threadIdx.x; j < NBUK; j += TPB)
        cur[j] = base[j] + tableB[chunk * NBUK + j];
    __syncthreads();
    for (int i = s + (int)threadIdx.x; i < e; i += TPB) {
        int r = b_rows[i];
        int c = b_cols[i];
        float v = b_vals[i];
        int p = atomicAdd(&cur[r >> SHIFT_B], 1);
        stg_rowB[p] = r;
        stg_cvB[p] = make_int2(c, __float_as_int(v));
    }
    __syncthreads();
    for (int j = threadIdx.x; j < NBUK; j += TPB)
        cur[j] = base[NBUK + j] + tableI[chunk * NBUK + j];
    __syncthreads();
    for (int i = s + (int)threadIdx.x; i < e; i += TPB) {
        int r = i_rows[i];
        int c = i_cols[i];
        float v = i_vals[i];
        int p = atomicAdd(&cur[r >> SHIFT_I], 1);
        stg_rowI[p] = r;
        stg_cvI[p] = make_int2(c, __float_as_int(v));
    }
}

// pass 3: per-bucket counting sort -> final CSR ev + row_ptr. One block per bucket.
__global__ __launch_bounds__(256) void k_bucket_sort(
        const int* __restrict__ stg_rowB, const int2* __restrict__ stg_cvB,
        const int* __restrict__ stg_rowI, const int2* __restrict__ stg_cvI,
        const int* __restrict__ base, const int* __restrict__ tot,
        int* __restrict__ b_row_ptr, int* __restrict__ i_row_ptr,
        int2* __restrict__ b_ev, int2* __restrict__ i_ev) {
    __shared__ int hist[256];
    __shared__ int scn[256];
    __shared__ int cursor[256];
    int id = blockIdx.x;
    int m = id / NBUK, b = id % NBUK;
    const int*  srow = m ? stg_rowI : stg_rowB;
    const int2* scv  = m ? stg_cvI  : stg_cvB;
    int2* ev = m ? i_ev : b_ev;
    int*  rp = m ? i_row_ptr : b_row_ptr;
    int shift = m ? SHIFT_I : SHIFT_B;
    int nrows = m ? N_ITEMS : N_BASKETS;
    int rpb   = 1 << shift;
    int rowbase = b << shift;
    int seg = base[m * NBUK + b];
    int cnt = tot[m * NBUK + b];
    int t = threadIdx.x;

    hist[t] = 0;
    __syncthreads();
    for (int i = t; i < cnt; i += TPB)
        atomicAdd(&hist[srow[seg + i] - rowbase], 1);
    __syncthreads();
    int v = hist[t];
    scn[t] = v;
    __syncthreads();
    for (int o = 1; o < 256; o <<= 1) {
        int tv = (t >= o) ? scn[t - o] : 0;
        __syncthreads();
        scn[t] += tv;
        __syncthreads();
    }
    int excl = scn[t] - v;
    int nlocal = min(rpb, nrows - rowbase);
    if (t < nlocal) rp[rowbase + t] = seg + excl;
    if (t == 0 && rowbase + nlocal == nrows) rp[nrows] = NNZ;
    cursor[t] = excl;
    __syncthreads();
    for (int i = t; i < cnt; i += TPB) {
        int r = srow[seg + i];
        int p = atomicAdd(&cursor[r - rowbase], 1);
        ev[seg + p] = scv[seg + i];
    }
}

// ---------------- CSR SpMM: one 64-lane wave per row, 8-deep pipelined gather ------
// fp32 accumulate; intermediates stored fp16 (half2 per lane), outputs fp32.
// SRC16: gather source is fp16 (256B rows) vs fp32 (512B rows).
// MODE 1: basket L1: out16 = h(acc); outf  = acc         (out_basket init)
// MODE 2: basket L2: out16 = h(acc); outf += acc
// MODE 3: basket L3: out16 = h(acc); outf  = (outf+acc)/3
// MODE 0: item L1/L2: out16 = h(acc)                      (cur fp16 only)
// MODE 4: item L3:   outf = (a0 + f(a1) + f(a2) + acc)/4  (final item rep)
template<int SRC16, int MODE>
__global__ __launch_bounds__(256) void k_spmm(const int* __restrict__ row_ptr,
                                              const int2* __restrict__ ev,
                                              const void* __restrict__ dense,
                                              void* __restrict__ out16,
                                              float* __restrict__ outf,
                                              const float* __restrict__ a0,
                                              const void* __restrict__ a1,
                                              const void* __restrict__ a2,
                                              int n_rows) {
    int wv   = threadIdx.x >> 6;
    int lane = threadIdx.x & 63;
    int row  = blockIdx.x * 4 + wv;
    if (row >= n_rows) return;
    int beg = row_ptr[row];
    int end = row_ptr[row + 1];
    beg = __builtin_amdgcn_readfirstlane(beg);
    end = __builtin_amdgcn_readfirstlane(end);

    const char* dbase = reinterpret_cast<const char*>(dense)
                        + (size_t)lane * (SRC16 ? 4 : 8);
    auto fetch = [&](int col) -> float2 {
        if (SRC16) {
            __half2 h = *reinterpret_cast<const __half2*>(dbase + ((size_t)col << 8));
            return __half22float2(h);
        } else {
            return *reinterpret_cast<const float2*>(dbase + ((size_t)col << 9));
        }
    };

    float ax = 0.f, ay = 0.f;
    int e = beg;
    for (; e + 8 <= end; e += 8) {
        int2 p[8];
        #pragma unroll
        for (int k = 0; k < 8; ++k) p[k] = ev[e + k];
        float2 d[8];
        #pragma unroll
        for (int k = 0; k < 8; ++k) d[k] = fetch(p[k].x);
        #pragma unroll
        for (int k = 0; k < 8; ++k) {
            float v = __int_as_float(p[k].y);
            ax = fmaf(v, d[k].x, ax); ay = fmaf(v, d[k].y, ay);
        }
    }
    for (; e + 4 <= end; e += 4) {
        int2 p[4];
        #pragma unroll
        for (int k = 0; k < 4; ++k) p[k] = ev[e + k];
        float2 d[4];
        #pragma unroll
        for (int k = 0; k < 4; ++k) d[k] = fetch(p[k].x);
        #pragma unroll
        for (int k = 0; k < 4; ++k) {
            float v = __int_as_float(p[k].y);
            ax = fmaf(v, d[k].x, ax); ay = fmaf(v, d[k].y, ay);
        }
    }
    for (; e < end; ++e) {
        int2 p = ev[e];
        float2 d = fetch(p.x);
        float v = __int_as_float(p.y);
        ax = fmaf(v, d.x, ax); ay = fmaf(v, d.y, ay);
    }

    size_t i64 = (size_t)row * 64 + (size_t)lane;   // float2 / half2 index
    if (MODE == 0 || MODE == 1 || MODE == 2 || MODE == 3) {
        reinterpret_cast<__half2*>(out16)[i64] =
            __float22half2_rn(make_float2(ax, ay));
    }
    if (MODE == 1) {
        reinterpret_cast<float2*>(outf)[i64] = make_float2(ax, ay);
    } else if (MODE == 2) {
        float2 s = reinterpret_cast<const float2*>(outf)[i64];
        s.x += ax; s.y += ay;
        reinterpret_cast<float2*>(outf)[i64] = s;
    } else if (MODE == 3) {
        float2 s = reinterpret_cast<const float2*>(outf)[i64];
        s.x = (s.x + ax) * (1.0f / 3.0f);
        s.y = (s.y + ay) * (1.0f / 3.0f);
        reinterpret_cast<float2*>(outf)[i64] = s;
    } else if (MODE == 4) {
        float2 s0 = reinterpret_cast<const float2*>(a0)[i64];
        float2 c1 = __half22float2(reinterpret_cast<const __half2*>(a1)[i64]);
        float2 c2 = __half22float2(reinterpret_cast<const __half2*>(a2)[i64]);
        float2 r;
        r.x = (s0.x + c1.x + c2.x + ax) * 0.25f;
        r.y = (s0.y + c1.y + c2.y + ay) * 0.25f;
        reinterpret_cast<float2*>(outf)[i64] = r;
    }
}

extern "C" void kernel_launch(void* const* d_in, const int* in_sizes, int n_in,
                              void* d_out, int out_size, void* d_ws, size_t ws_size,
                              hipStream_t stream) {
    const float* x      = (const float*)d_in[0];
    const int*   b_rows = (const int*)  d_in[1];
    const int*   b_cols = (const int*)  d_in[2];
    const float* b_vals = (const float*)d_in[3];
    const int*   i_rows = (const int*)  d_in[4];
    const int*   i_cols = (const int*)  d_in[5];
    const float* i_vals = (const float*)d_in[6];

    float* out        = (float*)d_out;
    float* out_item   = out;                              // [N_ITEMS * D]
    float* out_basket = out + (size_t)N_ITEMS * D;        // [N_BASKETS * D]

    char* ws = (char*)d_ws;
    size_t off = 0;
    auto alloc = [&](size_t bytes) -> char* {
        char* p = ws + off;
        off = (off + bytes + 255) & ~(size_t)255;
        return p;
    };
    int*   tableB    = (int*)  alloc((size_t)NBLK * NBUK * sizeof(int));
    int*   tableI    = (int*)  alloc((size_t)NBLK * NBUK * sizeof(int));
    int*   tot       = (int*)  alloc(2 * NBUK * sizeof(int));
    int*   base      = (int*)  alloc(2 * NBUK * sizeof(int));
    int*   b_row_ptr = (int*)  alloc((N_BASKETS + 1) * sizeof(int));
    int*   i_row_ptr = (int*)  alloc((N_ITEMS + 1) * sizeof(int));
    int2*  b_ev      = (int2*) alloc((size_t)NNZ * sizeof(int2));
    int2*  i_ev      = (int2*) alloc((size_t)NNZ * sizeof(int2));
    void*  basket16  = (void*) alloc((size_t)N_BASKETS * D * 2);   // 12.8 MB fp16
    void*  cur1_16   = (void*) alloc((size_t)N_ITEMS * D * 2);     // 25.6 MB fp16
    void*  cur2_16   = (void*) alloc((size_t)N_ITEMS * D * 2);     // 25.6 MB fp16
    // staging aliases cur1_16 (24 MB < 25.6 MB; dead before cur1_16 is written)
    char*  stg       = (char*)cur1_16;
    int*   stg_rowB  = (int*) stg;
    int2*  stg_cvB   = (int2*)(stg + (size_t)NNZ * sizeof(int));
    int*   stg_rowI  = (int*) (stg + (size_t)NNZ * 12);
    int2*  stg_cvI   = (int2*)(stg + (size_t)NNZ * 16);
    (void)ws_size; (void)in_sizes; (void)n_in; (void)out_size;

    // -------- atomic-free CSR build --------
    k_bucket_hist<<<NBLK, TPB, 0, stream>>>(b_rows, i_rows, tableB, tableI);
    k_col_scan<<<2 * NBUK, NBLK, 0, stream>>>(tableB, tableI, tot);
    k_base_scan<<<2, 512, 0, stream>>>(tot, base);
    k_route<<<NBLK, TPB, 0, stream>>>(b_rows, b_cols, b_vals,
                                      i_rows, i_cols, i_vals,
                                      tableB, tableI, base,
                                      stg_rowB, stg_cvB, stg_rowI, stg_cvI);
    k_bucket_sort<<<2 * NBUK, 256, 0, stream>>>(stg_rowB, stg_cvB, stg_rowI, stg_cvI,
                                                base, tot,
                                                b_row_ptr, i_row_ptr, b_ev, i_ev);

    const int GB = (N_BASKETS + 3) / 4;
    const int GI = (N_ITEMS + 3) / 4;

    // -------- layer 1 --------
    // basket1 = B @ x (fp32 gather); basket16 = h(basket1); out_basket = basket1
    k_spmm<0,1><<<GB, 256, 0, stream>>>(b_row_ptr, b_ev, x, basket16, out_basket,
                                        nullptr, nullptr, nullptr, N_BASKETS);
    // cur1 = I @ basket16 -> fp16 only
    k_spmm<1,0><<<GI, 256, 0, stream>>>(i_row_ptr, i_ev, basket16, cur1_16, nullptr,
                                        nullptr, nullptr, nullptr, N_ITEMS);
    // -------- layer 2 --------
    k_spmm<1,2><<<GB, 256, 0, stream>>>(b_row_ptr, b_ev, cur1_16, basket16, out_basket,
                                        nullptr, nullptr, nullptr, N_BASKETS);
    k_spmm<1,0><<<GI, 256, 0, stream>>>(i_row_ptr, i_ev, basket16, cur2_16, nullptr,
                                        nullptr, nullptr, nullptr, N_ITEMS);
    // -------- layer 3 --------
    k_spmm<1,3><<<GB, 256, 0, stream>>>(b_row_ptr, b_ev, cur2_16, basket16, out_basket,
                                        nullptr, nullptr, nullptr, N_BASKETS);
    // out_item = (x + f(cur1) + f(cur2) + I @ basket16)/4
    k_spmm<1,4><<<GI, 256, 0, stream>>>(i_row_ptr, i_ev, basket16, nullptr, out_item,
                                        x, cur1_16, cur2_16, N_ITEMS);
}